// Round 1
// baseline (880.936 us; speedup 1.0000x reference)
//
#include <hip/hip_runtime.h>

#define BB 32
#define NN 576
#define DD 1024
#define KK 128
#define HS_N 577

// ---------------- norm kernel: inv[b,n] = 1/||feats[b,n,:]|| ----------------
__global__ __launch_bounds__(256) void norm_kernel(const float* __restrict__ hs,
                                                   float* __restrict__ inv) {
    int row = blockIdx.x;              // b*NN + n
    int b = row / NN, n = row % NN;
    const float4* p = (const float4*)(hs + ((size_t)b * HS_N + n + 1) * DD);
    int t = threadIdx.x;
    float4 v = p[t];
    double s = (double)v.x * v.x + (double)v.y * v.y + (double)v.z * v.z + (double)v.w * v.w;
    for (int off = 32; off; off >>= 1) s += __shfl_xor(s, off);
    __shared__ double wsum[4];
    int lane = t & 63, w = t >> 6;
    if (lane == 0) wsum[w] = s;
    __syncthreads();
    if (t == 0) {
        double tot = wsum[0] + wsum[1] + wsum[2] + wsum[3];
        inv[row] = 1.0f / (float)sqrt(tot);
    }
}

// ---------------- sim GEMM (symmetric): only 45 upper-tri 64x64 tile pairs --
#define KC 16
#define LDT 68   // padded LDS stride
#define TLD 68   // transpose-bounce stride
__global__ __launch_bounds__(256) void sim_kernel(const float* __restrict__ hs,
                                                  const float* __restrict__ inv,
                                                  float* __restrict__ sim) {
    int b = blockIdx.z;
    int l = blockIdx.x;                // 0..44 -> (ti,tj), ti<=tj
    int ti = 0;
    while (l >= 9 - ti) { l -= 9 - ti; ti++; }
    int tj = ti + l;
    int m0 = ti * 64, n0 = tj * 64;
    const float* feats = hs + ((size_t)b * HS_N + 1) * DD;
    __shared__ float As[KC * LDT];
    __shared__ float Bs[KC * LDT];
    __shared__ float tile[64 * TLD];
    int t = threadIdx.x;
    int lrow = t >> 2, lc4 = (t & 3) << 2;     // 64 rows x 4 float4-cols
    float invA = inv[b * NN + m0 + lrow];
    float invB = inv[b * NN + n0 + lrow];
    const float* gA = feats + (size_t)(m0 + lrow) * DD + lc4;
    const float* gB = feats + (size_t)(n0 + lrow) * DD + lc4;
    int tx = t & 15, ty = t >> 4;
    float acc[4][4] = {};
    for (int k0 = 0; k0 < DD; k0 += KC) {
        float4 a = *(const float4*)(gA + k0);
        float4 bv = *(const float4*)(gB + k0);
        __syncthreads();
        // store transposed [k][m], scaled at load (matches reference normalize-then-dot)
        As[(lc4 + 0) * LDT + lrow] = a.x * invA;
        As[(lc4 + 1) * LDT + lrow] = a.y * invA;
        As[(lc4 + 2) * LDT + lrow] = a.z * invA;
        As[(lc4 + 3) * LDT + lrow] = a.w * invA;
        Bs[(lc4 + 0) * LDT + lrow] = bv.x * invB;
        Bs[(lc4 + 1) * LDT + lrow] = bv.y * invB;
        Bs[(lc4 + 2) * LDT + lrow] = bv.z * invB;
        Bs[(lc4 + 3) * LDT + lrow] = bv.w * invB;
        __syncthreads();
#pragma unroll
        for (int kk = 0; kk < KC; kk++) {
            float4 av = *(const float4*)&As[kk * LDT + (tx << 2)];
            float4 bw = *(const float4*)&Bs[kk * LDT + (ty << 2)];
            float aa[4] = {av.x, av.y, av.z, av.w};
            float bb[4] = {bw.x, bw.y, bw.z, bw.w};
#pragma unroll
            for (int i = 0; i < 4; i++)
#pragma unroll
                for (int j = 0; j < 4; j++) acc[i][j] += aa[i] * bb[j];
        }
    }
    // normal-orientation tile write (coalesced float4)
#pragma unroll
    for (int i = 0; i < 4; i++) {
        size_t m = m0 + (tx << 2) + i;
        float4 o = {acc[i][0], acc[i][1], acc[i][2], acc[i][3]};
        *(float4*)(sim + ((size_t)b * NN + m) * NN + n0 + (ty << 2)) = o;
    }
    if (ti != tj) {
        // mirror tile via LDS bounce; same float values -> bitwise symmetric
        __syncthreads();
#pragma unroll
        for (int i = 0; i < 4; i++) {
            float4 o = {acc[i][0], acc[i][1], acc[i][2], acc[i][3]};
            *(float4*)&tile[((tx << 2) + i) * TLD + (ty << 2)] = o;
        }
        __syncthreads();
#pragma unroll
        for (int r = 0; r < 4; r++) {
            int a = (tx << 2) + r;                 // local n index (output row)
            float4 o;
            o.x = tile[((ty << 2) + 0) * TLD + a];
            o.y = tile[((ty << 2) + 1) * TLD + a];
            o.z = tile[((ty << 2) + 2) * TLD + a];
            o.w = tile[((ty << 2) + 3) * TLD + a];
            *(float4*)(sim + ((size_t)b * NN + n0 + a) * NN + m0 + (ty << 2)) = o;
        }
    }
}

// -------- init gains on all CUs: g0[b,m] = sum_n max(sim[b,m,n],0) ----------
__global__ __launch_bounds__(256) void init_gain_kernel(const float* __restrict__ sim,
                                                        double* __restrict__ g0) {
    int b = blockIdx.y;
    int m = (blockIdx.x << 2) + (threadIdx.x >> 6);
    int lane = threadIdx.x & 63;
    const float* row = sim + ((size_t)b * NN + m) * NN;
    double s = 0.0;
#pragma unroll
    for (int j = 0; j < 9; j++) s += (double)fmaxf(row[(j << 6) + lane], 0.f);
    for (int off = 32; off; off >>= 1) s += __shfl_xor(s, off);
    if (lane == 0) g0[b * NN + m] = s;
}

// ------- selection: 9 waves x 1 candidate, 2 light barriers/step ------------
// v2 (this round): thread t owns candidate c0 = t (576 threads = 9 waves ->
// all 4 SIMDs active, vs previous 192x3 which left SIMD3 idle). Phase-1 delta
// math rewritten with the exact med3 identity:
//     max(x-nw,0) - max(x-o,0)  ==  o - med3(x, o, nw)      (o <= nw)
// -> fmaxf+fminf+sub+sel+cvt+f64add = ~16 cy/pair vs ~26 before, and the two
// f32-subtract roundings of the old form are gone (only o-m rounds, relative
// to the delta itself). A wave-vote skip (__any(x>o)) drops whole columns
// whose deltas are identically zero for all 64 lanes of the wave -- exact,
// and increasingly frequent late in the run as cmax grows.
__global__ __launch_bounds__(576, 1) void select_kernel(const float* __restrict__ sim,
                                                        const double* __restrict__ g0,
                                                        const float* __restrict__ cls,
                                                        float* __restrict__ out_idx,
                                                        int* __restrict__ gsorted) {
    int b = blockIdx.x;
    const float* S = sim + (size_t)b * NN * NN;
    int t = threadIdx.x, lane = t & 63, w = t >> 6;   // w in 0..8
    __shared__ float2 ovnw[NN];            // (old cmax, new cmax) per column
    __shared__ int    chlist[NN];
    __shared__ unsigned long long chmask[9];
    __shared__ double rv[9];
    __shared__ int    ri[9];
    __shared__ float  selseq[KK];
    __shared__ int    wcnt[9];

    double gg = g0[b * NN + t];
    double cl = (double)cls[b * NN + t];
    float mycmax = 0.f;
    bool sel = false;
    const int c0 = t;

    for (int k = 0; k < KK; k++) {
        // ---- phase 1: delta-update over step-(k-1) changed columns ----
        if (k > 0) {
            int pos = 0;
#pragma unroll
            for (int q = 0; q < 9; q++) {
                unsigned long long msk = chmask[q];
                if ((msk >> lane) & 1ull)
                    chlist[pos + __popcll(msk & ((1ull << lane) - 1ull))] = (q << 6) + lane;
                pos += __popcll(msk);
            }
            int cc = pos;
            for (int j = 0; j < cc; j += 16) {
                int nq[16]; float x[16]; float2 on[16];
#pragma unroll
                for (int q = 0; q < 16; q++) {
                    int f = j + q; f = (f < cc) ? f : cc - 1;
                    nq[q] = chlist[f];                    // wave-uniform
                }
#pragma unroll
                for (int q = 0; q < 16; q++) x[q] = S[(size_t)nq[q] * NN + t];
#pragma unroll
                for (int q = 0; q < 16; q++) on[q] = ovnw[nq[q]];  // broadcast
#pragma unroll
                for (int q = 0; q < 16; q++) {
                    float o = on[q].x, nw = on[q].y;
                    if (__any(x[q] > o)) {                // else all deltas == 0 exactly
                        bool val = (j + q) < cc;
                        float mm = fminf(fmaxf(x[q], o), nw);   // med3(x,o,nw)
                        float d = o - mm;                       // <= 0
                        gg += (double)(val ? d : 0.0f);
                    }
                }
            }
        }
        // ---- argmax: wave shuffle (strict >, smaller index on ties) ----
        double v = sel ? -1.0 : gg * cl;
        int idx = c0;
        for (int off = 32; off; off >>= 1) {
            double ov = __shfl_xor(v, off);
            int oi = __shfl_xor(idx, off);
            if (ov > v || (ov == v && oi < idx)) { v = ov; idx = oi; }
        }
        if (lane == 0) { rv[w] = v; ri[w] = idx; }
        __syncthreads();                           // A
        double bv = rv[0]; int mstar = ri[0];
#pragma unroll
        for (int q = 1; q < 9; q++) {
            double qv = rv[q]; int qi = ri[q];
            if (qv > bv || (qv == bv && qi < mstar)) { bv = qv; mstar = qi; }
        }
        // ---- tail: coalesced row load, cmax update, ballots ----
        float s0 = S[(size_t)mstar * NN + t];
        float o0 = mycmax, n0 = fmaxf(o0, s0);
        bool h0 = n0 > o0;
        unsigned long long m0 = __ballot(h0);
        ovnw[c0] = make_float2(o0, n0); mycmax = n0;
        if (lane == 0) chmask[w] = m0;
        if (c0 == mstar) { sel = true; selseq[k] = (float)(mstar + 1); }
        __syncthreads();                           // B
    }

    // ---- epilogue: write selection order + sorted gather list ----
    if (t < KK) out_idx[b * KK + t] = selseq[t];
    unsigned long long mk = __ballot(sel);
    if (lane == 0) wcnt[w] = __popcll(mk);
    __syncthreads();
    int r = __popcll(mk & ((1ull << lane) - 1));
    int pre = 0;
#pragma unroll
    for (int q = 0; q < 9; q++) if (q < w) pre += wcnt[q];
    if (sel) gsorted[b * KK + pre + r] = c0 + 1;
}

// ---------------- gather: dominant_tokens[b,j,:] = hs[b, gsorted, :] --------
__global__ __launch_bounds__(256) void gather_kernel(const float* __restrict__ hs,
                                                     const int* __restrict__ gsorted,
                                                     float* __restrict__ out) {
    int blk = blockIdx.x;
    int b = blk >> 7, j = blk & 127;
    int row = gsorted[b * KK + j];
    const float4* src = (const float4*)(hs + ((size_t)b * HS_N + row) * DD);
    float4* dst = (float4*)(out + ((size_t)b * KK + j) * DD);
    dst[threadIdx.x] = src[threadIdx.x];
}

extern "C" void kernel_launch(void* const* d_in, const int* in_sizes, int n_in,
                              void* d_out, int out_size, void* d_ws, size_t ws_size,
                              hipStream_t stream) {
    const float* hs = (const float*)d_in[0];
    const float* cls = (const float*)d_in[1];
    // workspace layout: sim (42.5MB) | X: inv (norm->sim) / g0 (init->select,
    // lifetimes disjoint, g0 overlays inv) | gsorted (16KB)
    float* sim = (float*)d_ws;
    char* xregion = (char*)(sim + (size_t)BB * NN * NN);
    float* inv = (float*)xregion;                  // BB*NN floats
    double* g0 = (double*)xregion;                 // BB*NN doubles (overlay)
    int* gsorted = (int*)(xregion + (size_t)BB * NN * sizeof(double));
    float* out_tokens = (float*)d_out;                       // [B,K,D] fp32
    float* out_idx = out_tokens + (size_t)BB * KK * DD;      // [B,K] indices as fp32

    norm_kernel<<<BB * NN, 256, 0, stream>>>(hs, inv);
    sim_kernel<<<dim3(45, 1, BB), 256, 0, stream>>>(hs, inv, sim);
    init_gain_kernel<<<dim3(NN / 4, BB), 256, 0, stream>>>(sim, g0);
    select_kernel<<<BB, 576, 0, stream>>>(sim, g0, cls, out_idx, gsorted);
    gather_kernel<<<BB * KK, 256, 0, stream>>>(hs, gsorted, out_tokens);
}